// Round 6
// baseline (40.598 us; speedup 1.0000x reference)
//
#include <hip/hip_runtime.h>

// P = dW/dF for W(F) = 8*tr(C) + 10*J^2 - 56*log(J) + 0.2*(I4^2 + I5^2) - 44
// C = F^T F, J = det F, G = diag(4, .5, .5), I4 = tr(C G), I5 = tr(cof(C) G)
// Analytic gradient:
//   P = 16 F + [20 J^2 - 56 + 0.8 I5^2] F^-T + 0.8 I4 * F G - 0.8 I5 * F^-T G cofC
// with F^-T = cof(F)/J, cofC = cof(C).
//
// R5: widen GLOBAL access to float4 (16B/lane -- the width m13's 6.3 TB/s
//     ceiling was measured at) while keeping 100% nominal occupancy:
//     512 threads/block, 1024-sample tile = 2304 f4 = 36 KB LDS ->
//     4 blocks/CU x 8 waves = 32 waves/CU. Staging: 4 full f4 iters +
//     half-iter by waves 0-3 (wave-uniform). Compute unchanged: f2 LDS
//     reads at odd stride 9 (conflict-free), 2 samples/thread.
//     No min-waves launch bound (R3: forced VGPR=32 -> spills).

typedef float f2 __attribute__((ext_vector_type(2)));
typedef float f4 __attribute__((ext_vector_type(4)));

#define BLOCK_THREADS 512
#define SAMPLES_PER_BLOCK 1024
#define F4_PER_BLOCK (SAMPLES_PER_BLOCK * 9 / 4)   // 2304 f4 = 36 KB

__global__ __launch_bounds__(512) void pk1_grad_kernel(
    const f4* __restrict__ Fin, f4* __restrict__ Pout, int total4)
{
    __shared__ f4 lds4[F4_PER_BLOCK];
    f2* lds2 = reinterpret_cast<f2*>(lds4);
    const int t = threadIdx.x;
    const int base4 = blockIdx.x * F4_PER_BLOCK;

    // ---- coalesced staging: global -> LDS, 16B/lane ----
#pragma unroll
    for (int j = 0; j < 4; ++j) {
        int i = j * BLOCK_THREADS + t;          // 0..2047
        int g = base4 + i;
        f4 v;
        if (g < total4) v = Fin[g];
        else { v.x = 1.0f; v.y = 0.0f; v.z = 0.0f; v.w = 1.0f; } // benign pad
        lds4[i] = v;
    }
    if (t < 256) {                               // waves 0-3: last 256 f4
        int i = 4 * BLOCK_THREADS + t;           // 2048..2303
        int g = base4 + i;
        f4 v;
        if (g < total4) v = Fin[g];
        else { v.x = 1.0f; v.y = 0.0f; v.z = 0.0f; v.w = 1.0f; }
        lds4[i] = v;
    }
    __syncthreads();

    // ---- per-thread: 2 samples = 18 floats = 9 f2 at stride 9 (conflict-free) ----
    float buf[18];
#pragma unroll
    for (int q = 0; q < 9; ++q) {
        f2 v = lds2[t * 9 + q];
        buf[2 * q]     = v.x;
        buf[2 * q + 1] = v.y;
    }

#pragma unroll
    for (int s = 0; s < 2; ++s) {
        float f[9];
#pragma unroll
        for (int k = 0; k < 9; ++k) f[k] = buf[s * 9 + k];

        // cof(F): F^-T = cof(F)/J
        float c00 = f[4]*f[8] - f[5]*f[7];
        float c01 = f[5]*f[6] - f[3]*f[8];
        float c02 = f[3]*f[7] - f[4]*f[6];
        float c10 = f[2]*f[7] - f[1]*f[8];
        float c11 = f[0]*f[8] - f[2]*f[6];
        float c12 = f[1]*f[6] - f[0]*f[7];
        float c20 = f[1]*f[5] - f[2]*f[4];
        float c21 = f[2]*f[3] - f[0]*f[5];
        float c22 = f[0]*f[4] - f[1]*f[3];
        float J    = f[0]*c00 + f[1]*c01 + f[2]*c02;
        float invJ = 1.0f / J;

        // C = F^T F (symmetric)
        float C00 = f[0]*f[0] + f[3]*f[3] + f[6]*f[6];
        float C11 = f[1]*f[1] + f[4]*f[4] + f[7]*f[7];
        float C22 = f[2]*f[2] + f[5]*f[5] + f[8]*f[8];
        float C01 = f[0]*f[1] + f[3]*f[4] + f[6]*f[7];
        float C02 = f[0]*f[2] + f[3]*f[5] + f[6]*f[8];
        float C12 = f[1]*f[2] + f[4]*f[5] + f[7]*f[8];

        float I4 = 4.0f*C00 + 0.5f*(C11 + C22);

        // cof(C) (symmetric)
        float K00 = C11*C22 - C12*C12;
        float K11 = C00*C22 - C02*C02;
        float K22 = C00*C11 - C01*C01;
        float K01 = C02*C12 - C01*C22;
        float K02 = C01*C12 - C02*C11;
        float K12 = C01*C02 - C00*C12;

        float I5 = 4.0f*K00 + 0.5f*(K11 + K22);

        float J2    = J * J;
        float alpha = (20.0f*J2 - 56.0f + 0.8f*I5*I5) * invJ;  // coeff on cof(F)
        float beta  = 0.8f * I4;                                // coeff on F G
        float gamma = -0.8f * I5 * invJ;                        // coeff on cof(F) G cofC

        float cf[3][3] = {{c00,c01,c02},{c10,c11,c12},{c20,c21,c22}};
        float K[3][3]  = {{K00,K01,K02},{K01,K11,K12},{K02,K12,K22}};
        const float gv[3] = {4.0f, 0.5f, 0.5f};

#pragma unroll
        for (int i = 0; i < 3; ++i) {
            float a0 = cf[i][0] * 4.0f;
            float a1 = cf[i][1] * 0.5f;
            float a2 = cf[i][2] * 0.5f;
#pragma unroll
            for (int j = 0; j < 3; ++j) {
                float M = a0 * K[0][j] + a1 * K[1][j] + a2 * K[2][j];
                buf[s * 9 + 3 * i + j] =
                      (16.0f + beta * gv[j]) * f[3 * i + j]
                    + alpha * cf[i][j]
                    + gamma * M;
            }
        }
    }

    // ---- results back to LDS (thread-private f2 slots), then barrier ----
#pragma unroll
    for (int q = 0; q < 9; ++q) {
        f2 v;
        v.x = buf[2 * q];
        v.y = buf[2 * q + 1];
        lds2[t * 9 + q] = v;
    }
    __syncthreads();

    // ---- coalesced cached stores: LDS -> global, 16B/lane ----
#pragma unroll
    for (int j = 0; j < 4; ++j) {
        int i = j * BLOCK_THREADS + t;
        int g = base4 + i;
        if (g < total4) Pout[g] = lds4[i];
    }
    if (t < 256) {
        int i = 4 * BLOCK_THREADS + t;
        int g = base4 + i;
        if (g < total4) Pout[g] = lds4[i];
    }
}

extern "C" void kernel_launch(void* const* d_in, const int* in_sizes, int n_in,
                              void* d_out, int out_size, void* d_ws, size_t ws_size,
                              hipStream_t stream) {
    const f4* F = (const f4*)d_in[0];
    f4* P = (f4*)d_out;
    int total4 = in_sizes[0] / 4;             // 6,750,000 f4
    int blocks = (total4 + F4_PER_BLOCK - 1) / F4_PER_BLOCK;
    pk1_grad_kernel<<<blocks, BLOCK_THREADS, 0, stream>>>(F, P, total4);
}

// Round 7
// 38.678 us; speedup vs baseline: 1.0496x; 1.0496x over previous
//
#include <hip/hip_runtime.h>

// P = dW/dF for W(F) = 8*tr(C) + 10*J^2 - 56*log(J) + 0.2*(I4^2 + I5^2) - 44
// C = F^T F, J = det F, G = diag(4, .5, .5), I4 = tr(C G), I5 = tr(cof(C) G)
// Analytic gradient:
//   P = 16 F + [20 J^2 - 56 + 0.8 I5^2] F^-T + 0.8 I4 * F G - 0.8 I5 * F^-T G cofC
// with F^-T = cof(F)/J, cofC = cof(C).
//
// R6: software-pipelined multi-tile blocks. 1024 blocks (4/CU at 36 KB LDS),
//     each block walks tiles grid-stride with REGISTER PREFETCH of tile k+1
//     issued during tile k's compute (T14 issue-early/write-late). Separate
//     input (X) and output (Y) LDS buffers keep the schedule at 2 barriers
//     per tile, race-free (a wave past B2 implies all X-reads of that tile
//     are done). f2 global path, stride-9 LDS (conflict-free), natural VGPR
//     (no min-waves bound -- R3 spill lesson).

typedef float f2 __attribute__((ext_vector_type(2)));

#define TPB 256
#define SAMPLES_PER_TILE 512
#define F2_PER_TILE (SAMPLES_PER_TILE * 9 / 2)   // 2304 f2 = 18 KB
#define NBLOCKS 1024

__global__ __launch_bounds__(TPB) void pk1_grad_kernel(
    const f2* __restrict__ Fin, f2* __restrict__ Pout, int total2, int ntiles)
{
    __shared__ f2 ldsX[F2_PER_TILE];   // staged input tile
    __shared__ f2 ldsY[F2_PER_TILE];   // staged output tile
    const int t = threadIdx.x;

    // ---- prologue: load first tile into prefetch registers ----
    f2 pre[9];
    {
        const int base2 = blockIdx.x * F2_PER_TILE;
#pragma unroll
        for (int q = 0; q < 9; ++q) {
            int g = base2 + q * TPB + t;
            if (g < total2) pre[q] = Fin[g];
            else { pre[q].x = 1.0f; pre[q].y = 1.0f; }   // benign pad
        }
    }

    for (int tile = blockIdx.x; tile < ntiles; tile += NBLOCKS) {
        const int base2 = tile * F2_PER_TILE;

        // ---- stage current tile regs -> LDS X ----
#pragma unroll
        for (int q = 0; q < 9; ++q) ldsX[q * TPB + t] = pre[q];
        __syncthreads();   // B1: X ready

        // ---- issue prefetch for tile k+1 (in flight during compute/store) ----
        const int ntile = tile + NBLOCKS;
        if (ntile < ntiles) {                 // block-uniform branch
            const int nbase2 = ntile * F2_PER_TILE;
#pragma unroll
            for (int q = 0; q < 9; ++q) {
                int g = nbase2 + q * TPB + t;
                if (g < total2) pre[q] = Fin[g];
                else { pre[q].x = 1.0f; pre[q].y = 1.0f; }
            }
        }

        // ---- compute 2 samples from X (stride-9 f2 reads: conflict-free) ----
        float buf[18];
#pragma unroll
        for (int q = 0; q < 9; ++q) {
            f2 v = ldsX[t * 9 + q];
            buf[2 * q]     = v.x;
            buf[2 * q + 1] = v.y;
        }

#pragma unroll
        for (int s = 0; s < 2; ++s) {
            float f[9];
#pragma unroll
            for (int k = 0; k < 9; ++k) f[k] = buf[s * 9 + k];

            // cof(F): F^-T = cof(F)/J
            float c00 = f[4]*f[8] - f[5]*f[7];
            float c01 = f[5]*f[6] - f[3]*f[8];
            float c02 = f[3]*f[7] - f[4]*f[6];
            float c10 = f[2]*f[7] - f[1]*f[8];
            float c11 = f[0]*f[8] - f[2]*f[6];
            float c12 = f[1]*f[6] - f[0]*f[7];
            float c20 = f[1]*f[5] - f[2]*f[4];
            float c21 = f[2]*f[3] - f[0]*f[5];
            float c22 = f[0]*f[4] - f[1]*f[3];
            float J    = f[0]*c00 + f[1]*c01 + f[2]*c02;
            float invJ = 1.0f / J;

            // C = F^T F (symmetric)
            float C00 = f[0]*f[0] + f[3]*f[3] + f[6]*f[6];
            float C11 = f[1]*f[1] + f[4]*f[4] + f[7]*f[7];
            float C22 = f[2]*f[2] + f[5]*f[5] + f[8]*f[8];
            float C01 = f[0]*f[1] + f[3]*f[4] + f[6]*f[7];
            float C02 = f[0]*f[2] + f[3]*f[5] + f[6]*f[8];
            float C12 = f[1]*f[2] + f[4]*f[5] + f[7]*f[8];

            float I4 = 4.0f*C00 + 0.5f*(C11 + C22);

            // cof(C) (symmetric)
            float K00 = C11*C22 - C12*C12;
            float K11 = C00*C22 - C02*C02;
            float K22 = C00*C11 - C01*C01;
            float K01 = C02*C12 - C01*C22;
            float K02 = C01*C12 - C02*C11;
            float K12 = C01*C02 - C00*C12;

            float I5 = 4.0f*K00 + 0.5f*(K11 + K22);

            float J2    = J * J;
            float alpha = (20.0f*J2 - 56.0f + 0.8f*I5*I5) * invJ;
            float beta  = 0.8f * I4;
            float gamma = -0.8f * I5 * invJ;

            float cf[3][3] = {{c00,c01,c02},{c10,c11,c12},{c20,c21,c22}};
            float K[3][3]  = {{K00,K01,K02},{K01,K11,K12},{K02,K12,K22}};
            const float gv[3] = {4.0f, 0.5f, 0.5f};

#pragma unroll
            for (int i = 0; i < 3; ++i) {
                float a0 = cf[i][0] * 4.0f;
                float a1 = cf[i][1] * 0.5f;
                float a2 = cf[i][2] * 0.5f;
#pragma unroll
                for (int j = 0; j < 3; ++j) {
                    float M = a0 * K[0][j] + a1 * K[1][j] + a2 * K[2][j];
                    buf[s * 9 + 3 * i + j] =
                          (16.0f + beta * gv[j]) * f[3 * i + j]
                        + alpha * cf[i][j]
                        + gamma * M;
                }
            }
        }

        // ---- results -> LDS Y (thread-private stride-9 slots) ----
#pragma unroll
        for (int q = 0; q < 9; ++q) {
            f2 v;
            v.x = buf[2 * q];
            v.y = buf[2 * q + 1];
            ldsY[t * 9 + q] = v;
        }
        __syncthreads();   // B2: Y ready (and all X-reads of this tile done)

        // ---- coalesced cached stores: Y -> global ----
#pragma unroll
        for (int q = 0; q < 9; ++q) {
            int g = base2 + q * TPB + t;
            if (g < total2) Pout[g] = ldsY[q * TPB + t];
        }
        // next iteration overwrites X (disjoint from Y) then hits B1 -- safe.
    }
}

extern "C" void kernel_launch(void* const* d_in, const int* in_sizes, int n_in,
                              void* d_out, int out_size, void* d_ws, size_t ws_size,
                              hipStream_t stream) {
    const f2* F = (const f2*)d_in[0];
    f2* P = (f2*)d_out;
    int total2 = in_sizes[0] / 2;                         // 13,500,000 f2
    int ntiles = (total2 + F2_PER_TILE - 1) / F2_PER_TILE; // 5860
    pk1_grad_kernel<<<NBLOCKS, TPB, 0, stream>>>(F, P, total2, ntiles);
}